// Round 7
// baseline (110.325 us; speedup 1.0000x reference)
//
#include <hip/hip_runtime.h>

typedef float f32x4 __attribute__((ext_vector_type(4)));
typedef int   i32x4 __attribute__((ext_vector_type(4)));
typedef int   i32x8 __attribute__((ext_vector_type(8)));

#define D 128
#define NBLK 256   // persistent: 1 block/CU, all resident (spin-barrier safe)

// ---------------------------------------------------------------------------
// Single persistent kernel:
//   phase 0: each block normalizes 32 rows of both matrices -> fp8 e4m3 in ws,
//            exact-f32 diag partial -> diagP[bid]
//   grid barrier (ticket + agent fences; 1 block/CU so spin is deadlock-free)
//   phase 1: fp8-MX GEMM (R6 structure: wave tile 128x32, af hoisted, B dbuf),
//            relu-sum with 4 independent chains, ticket-fused finalize.
// ---------------------------------------------------------------------------
__global__ __launch_bounds__(512, 2) void fused_loss_kernel(
    const float* __restrict__ anc, const float* __restrict__ pos,
    unsigned char* __restrict__ wsA, unsigned char* __restrict__ wsP,
    float* __restrict__ partials, float* __restrict__ diagP,
    int* __restrict__ c0, int* __restrict__ c1,
    float* __restrict__ out, float invBB) {
  __shared__ __align__(16) unsigned char ldsA[256 * 128];      // 32 KB
  __shared__ __align__(16) unsigned char ldsB[2][128 * 128];   // 2 x 16 KB
  __shared__ float wpart[8];
  __shared__ int lastFlag;
  const int tid = threadIdx.x;
  const int bid = blockIdx.x;
  const int w = tid >> 6, l = tid & 63;

  // ================= phase 0: normalize rows bid*32 .. bid*32+31 ============
  {
    const int rl = tid >> 4, l16 = tid & 15;
    const int row = bid * 32 + rl;
    const float* ar = anc + (size_t)row * D + l16 * 8;
    const float* pr = pos + (size_t)row * D + l16 * 8;
    float4 a0 = *(const float4*)ar, a1 = *(const float4*)(ar + 4);
    float4 p0 = *(const float4*)pr, p1 = *(const float4*)(pr + 4);
    float av[8] = {a0.x, a0.y, a0.z, a0.w, a1.x, a1.y, a1.z, a1.w};
    float pv[8] = {p0.x, p0.y, p0.z, p0.w, p1.x, p1.y, p1.z, p1.w};
    float ssa = 0.f, ssp = 0.f;
#pragma unroll
    for (int k = 0; k < 8; ++k) { ssa += av[k] * av[k]; ssp += pv[k] * pv[k]; }
#pragma unroll
    for (int off = 1; off < 16; off <<= 1) {
      ssa += __shfl_xor(ssa, off);
      ssp += __shfl_xor(ssp, off);
    }
    const float sa = 1.f / fmaxf(sqrtf(ssa), 1e-8f);
    const float sp = 1.f / fmaxf(sqrtf(ssp), 1e-8f);
    float an[8], pn[8];
    float dot = 0.f;
#pragma unroll
    for (int k = 0; k < 8; ++k) {
      an[k] = av[k] * sa;
      pn[k] = pv[k] * sp;
      dot += an[k] * pn[k];
    }
    int wa0 = __builtin_amdgcn_cvt_pk_fp8_f32(an[0], an[1], 0, false);
    wa0 = __builtin_amdgcn_cvt_pk_fp8_f32(an[2], an[3], wa0, true);
    int wa1 = __builtin_amdgcn_cvt_pk_fp8_f32(an[4], an[5], 0, false);
    wa1 = __builtin_amdgcn_cvt_pk_fp8_f32(an[6], an[7], wa1, true);
    int wp0 = __builtin_amdgcn_cvt_pk_fp8_f32(pn[0], pn[1], 0, false);
    wp0 = __builtin_amdgcn_cvt_pk_fp8_f32(pn[2], pn[3], wp0, true);
    int wp1 = __builtin_amdgcn_cvt_pk_fp8_f32(pn[4], pn[5], 0, false);
    wp1 = __builtin_amdgcn_cvt_pk_fp8_f32(pn[6], pn[7], wp1, true);
    *(int2*)(wsA + (size_t)row * D + l16 * 8) = make_int2(wa0, wa1);
    *(int2*)(wsP + (size_t)row * D + l16 * 8) = make_int2(wp0, wp1);
#pragma unroll
    for (int off = 1; off < 16; off <<= 1) dot += __shfl_xor(dot, off);
    // lane l16==0 of each 16-group holds this row's diag correction
    float c = (l16 == 0) ? (1.f - dot - fmaxf(dot, 0.f)) : 0.f;
#pragma unroll
    for (int off = 1; off < 64; off <<= 1) c += __shfl_xor(c, off);
    if (l == 0) wpart[w] = c;
    __syncthreads();
    if (tid == 0) {
      float sD = 0.f;
#pragma unroll
      for (int i = 0; i < 8; ++i) sD += wpart[i];
      diagP[bid] = sD;
    }
  }

  // ================= grid barrier (release -> ticket -> acquire) ============
  __threadfence();            // writeback: ws/diagP stores visible device-wide
  __syncthreads();
  if (tid == 0) {
    __hip_atomic_fetch_add(c0, 1, __ATOMIC_RELEASE, __HIP_MEMORY_SCOPE_AGENT);
    while (__hip_atomic_load(c0, __ATOMIC_RELAXED, __HIP_MEMORY_SCOPE_AGENT) <
           NBLK)
      __builtin_amdgcn_s_sleep(2);
  }
  __syncthreads();
  __threadfence();            // invalidate: see other blocks' ws writes

  // ================= phase 1: fp8-MX GEMM (R6-validated structure) ==========
  const int r16 = l & 15, kg = l >> 4;
  const int wrow = w >> 2, wcol = w & 3;   // wave tile 128 rows x 32 cols
  const int rp = bid >> 3;                 // row panel 0..31 (256 rows)
  const int cg = bid & 7;                  // col group 0..7 (XCD-pinned)

  const unsigned char* gA = wsA + (size_t)rp * 256 * D;
#pragma unroll
  for (int it = 0; it < 4; ++it) {         // stage A panel (32KB)
    const int g = it * 512 + tid;
    const int r = g >> 3, sl = g & 7;
    const int goff = r * 128 + ((sl ^ (r & 7)) * 16);
    const int lbase = (it * 512 + w * 64) * 16;
    __builtin_amdgcn_global_load_lds(
        (const __attribute__((address_space(1))) char*)(gA + goff),
        (__attribute__((address_space(3))) char*)((char*)ldsA + lbase), 16, 0, 0);
  }
  {                                        // stage B tile 0 (16KB)
    const unsigned char* gBt = wsP + (size_t)(cg * 1024) * D;
#pragma unroll
    for (int it = 0; it < 2; ++it) {
      const int g = it * 512 + tid;
      const int r = g >> 3, sl = g & 7;
      const int goff = r * 128 + ((sl ^ (r & 7)) * 16);
      const int lbase = (it * 512 + w * 64) * 16;
      __builtin_amdgcn_global_load_lds(
          (const __attribute__((address_space(1))) char*)(gBt + goff),
          (__attribute__((address_space(3))) char*)((char*)ldsB[0] + lbase), 16, 0, 0);
    }
  }
  __syncthreads();

  i32x8 af[8];                             // hoist A fragments (64 VGPR)
#pragma unroll
  for (int m = 0; m < 8; ++m) {
    const int r = wrow * 128 + m * 16 + r16;
    const unsigned char* base = (const unsigned char*)ldsA + r * 128;
    i32x4 lo = *(const i32x4*)(base + (((2 * kg) ^ (r & 7)) * 16));
    i32x4 hi = *(const i32x4*)(base + (((2 * kg + 1) ^ (r & 7)) * 16));
    af[m] = __builtin_shufflevector(lo, hi, 0, 1, 2, 3, 4, 5, 6, 7);
  }

  float s0 = 0.f, s1 = 0.f, s2 = 0.f, s3 = 0.f;   // 4 independent chains
  for (int t = 0; t < 8; ++t) {
    if (t < 7) {   // stage next B tile (hides under 16-MFMA phase)
      const unsigned char* gBt = wsP + (size_t)(cg * 1024 + (t + 1) * 128) * D;
      char* lB = (char*)ldsB[(t + 1) & 1];
#pragma unroll
      for (int it = 0; it < 2; ++it) {
        const int g = it * 512 + tid;
        const int r = g >> 3, sl = g & 7;
        const int goff = r * 128 + ((sl ^ (r & 7)) * 16);
        const int lbase = (it * 512 + w * 64) * 16;
        __builtin_amdgcn_global_load_lds(
            (const __attribute__((address_space(1))) char*)(gBt + goff),
            (__attribute__((address_space(3))) char*)(lB + lbase), 16, 0, 0);
      }
    }

    const unsigned char* lB = (const unsigned char*)ldsB[t & 1];
    i32x8 bfr[2];
#pragma unroll
    for (int n = 0; n < 2; ++n) {
      const int r = wcol * 32 + n * 16 + r16;
      const unsigned char* base = lB + r * 128;
      i32x4 lo = *(const i32x4*)(base + (((2 * kg) ^ (r & 7)) * 16));
      i32x4 hi = *(const i32x4*)(base + (((2 * kg + 1) ^ (r & 7)) * 16));
      bfr[n] = __builtin_shufflevector(lo, hi, 0, 1, 2, 3, 4, 5, 6, 7);
    }

    f32x4 acc[8][2] = {};
    __builtin_amdgcn_s_setprio(1);
#pragma unroll
    for (int m = 0; m < 8; ++m)
#pragma unroll
      for (int n = 0; n < 2; ++n)
        acc[m][n] = __builtin_amdgcn_mfma_scale_f32_16x16x128_f8f6f4(
            af[m], bfr[n], acc[m][n], 0, 0,   // cbsz=fp8, blgp=fp8
            0, 0x7f7f7f7f, 0, 0x7f7f7f7f);    // scales = 1.0
    __builtin_amdgcn_s_setprio(0);

#pragma unroll
    for (int m = 0; m < 8; ++m)
#pragma unroll
      for (int n = 0; n < 2; ++n) {
        s0 += fmaxf(acc[m][n][0], 0.f);
        s1 += fmaxf(acc[m][n][1], 0.f);
        s2 += fmaxf(acc[m][n][2], 0.f);
        s3 += fmaxf(acc[m][n][3], 0.f);
      }

    __syncthreads();
  }

  // ================= block partial + ticket-fused finalize ==================
  float s = (s0 + s1) + (s2 + s3);
#pragma unroll
  for (int off = 32; off >= 1; off >>= 1) s += __shfl_xor(s, off);
  if (l == 0) wpart[w] = s;
  __syncthreads();
  if (tid == 0) {
    float b = 0.f;
#pragma unroll
    for (int i = 0; i < 8; ++i) b += wpart[i];
    __hip_atomic_store(&partials[bid], b, __ATOMIC_RELAXED,
                       __HIP_MEMORY_SCOPE_AGENT);
    __threadfence();
    const int ticket = __hip_atomic_fetch_add(c1, 1, __ATOMIC_ACQ_REL,
                                              __HIP_MEMORY_SCOPE_AGENT);
    lastFlag = (ticket == NBLK - 1) ? 1 : 0;
  }
  __syncthreads();

  if (lastFlag) {
    __threadfence();
    float v = 0.f;
    if (tid < NBLK)
      v = __hip_atomic_load(&partials[tid], __ATOMIC_RELAXED,
                            __HIP_MEMORY_SCOPE_AGENT) +
          diagP[tid];
#pragma unroll
    for (int off = 32; off >= 1; off >>= 1) v += __shfl_xor(v, off);
    if (l == 0) wpart[w] = v;
    __syncthreads();
    if (tid == 0) {
      float tot = 0.f;
#pragma unroll
      for (int i = 0; i < 8; ++i) tot += wpart[i];
      out[0] = tot * invBB;
    }
  }
}

extern "C" void kernel_launch(void* const* d_in, const int* in_sizes, int n_in,
                              void* d_out, int out_size, void* d_ws, size_t ws_size,
                              hipStream_t stream) {
  const float* pos = (const float*)d_in[0];  // hid_positive
  const float* anc = (const float*)d_in[1];  // hid_anchor
  const int B = in_sizes[0] / D;             // 8192

  char* ws = (char*)d_ws;
  unsigned char* wsA = (unsigned char*)ws;                      // B*D fp8 (1MB)
  unsigned char* wsP = (unsigned char*)(ws + (size_t)B * D);    // B*D fp8 (1MB)
  float* partials = (float*)(ws + (size_t)2 * B * D);           // 256 f32
  float* diagP = partials + NBLK;                               // 256 f32
  int* counters = (int*)(diagP + NBLK);                         // c0, c1

  const float invBB = 1.0f / ((float)B * (float)B);

  hipMemsetAsync(counters, 0, 8, stream);    // zero c0,c1 each call
  fused_loss_kernel<<<NBLK, 512, 0, stream>>>(anc, pos, wsA, wsP, partials,
                                              diagP, counters, counters + 1,
                                              (float*)d_out, invBB);
}

// Round 8
// 31.393 us; speedup vs baseline: 3.5143x; 3.5143x over previous
//
#include <hip/hip_runtime.h>

typedef float f32x4 __attribute__((ext_vector_type(4)));
typedef int   i32x4 __attribute__((ext_vector_type(4)));
typedef int   i32x8 __attribute__((ext_vector_type(8)));

#define D 128
#define NBLK 256

// ---------------------------------------------------------------------------
// Normalize: one block = 16 rows x 16 lanes. fp8(e4m3) normalized rows -> ws,
// exact-f32 diag partial -> diagP[bid]; block 0 zeroes the gemm ticket.
// (Validated verbatim since R5: absmax 0.0.)
// ---------------------------------------------------------------------------
__global__ void normalize_diag_kernel(const float* __restrict__ anc,
                                      const float* __restrict__ pos,
                                      unsigned char* __restrict__ wsA,
                                      unsigned char* __restrict__ wsP,
                                      float* __restrict__ diagP,
                                      int* __restrict__ counter) {
  if (blockIdx.x == 0 && threadIdx.x == 0)
    __hip_atomic_store(counter, 0, __ATOMIC_RELAXED, __HIP_MEMORY_SCOPE_AGENT);
  __shared__ float rowc[16];
  const int t = threadIdx.x;
  const int rl = t >> 4, l16 = t & 15;
  const int row = blockIdx.x * 16 + rl;
  const float* ar = anc + (size_t)row * D + l16 * 8;
  const float* pr = pos + (size_t)row * D + l16 * 8;
  float4 a0 = *(const float4*)ar, a1 = *(const float4*)(ar + 4);
  float4 p0 = *(const float4*)pr, p1 = *(const float4*)(pr + 4);
  float av[8] = {a0.x, a0.y, a0.z, a0.w, a1.x, a1.y, a1.z, a1.w};
  float pv[8] = {p0.x, p0.y, p0.z, p0.w, p1.x, p1.y, p1.z, p1.w};
  float ssa = 0.f, ssp = 0.f;
#pragma unroll
  for (int k = 0; k < 8; ++k) { ssa += av[k] * av[k]; ssp += pv[k] * pv[k]; }
#pragma unroll
  for (int off = 1; off < 16; off <<= 1) {
    ssa += __shfl_xor(ssa, off);
    ssp += __shfl_xor(ssp, off);
  }
  const float sa = 1.f / fmaxf(sqrtf(ssa), 1e-8f);
  const float sp = 1.f / fmaxf(sqrtf(ssp), 1e-8f);
  float an[8], pn[8];
  float dot = 0.f;
#pragma unroll
  for (int k = 0; k < 8; ++k) {
    an[k] = av[k] * sa;
    pn[k] = pv[k] * sp;
    dot += an[k] * pn[k];
  }
  int wa0 = __builtin_amdgcn_cvt_pk_fp8_f32(an[0], an[1], 0, false);
  wa0 = __builtin_amdgcn_cvt_pk_fp8_f32(an[2], an[3], wa0, true);
  int wa1 = __builtin_amdgcn_cvt_pk_fp8_f32(an[4], an[5], 0, false);
  wa1 = __builtin_amdgcn_cvt_pk_fp8_f32(an[6], an[7], wa1, true);
  int wp0 = __builtin_amdgcn_cvt_pk_fp8_f32(pn[0], pn[1], 0, false);
  wp0 = __builtin_amdgcn_cvt_pk_fp8_f32(pn[2], pn[3], wp0, true);
  int wp1 = __builtin_amdgcn_cvt_pk_fp8_f32(pn[4], pn[5], 0, false);
  wp1 = __builtin_amdgcn_cvt_pk_fp8_f32(pn[6], pn[7], wp1, true);
  *(int2*)(wsA + (size_t)row * D + l16 * 8) = make_int2(wa0, wa1);
  *(int2*)(wsP + (size_t)row * D + l16 * 8) = make_int2(wp0, wp1);
#pragma unroll
  for (int off = 1; off < 16; off <<= 1) dot += __shfl_xor(dot, off);
  if (l16 == 0) rowc[rl] = 1.f - dot - fmaxf(dot, 0.f);
  __syncthreads();
  if (t == 0) {
    float s = 0.f;
#pragma unroll
    for (int i = 0; i < 16; ++i) s += rowc[i];
    diagP[blockIdx.x] = s;
  }
}

// ---------------------------------------------------------------------------
// fp8 MX GEMM, counted-vmcnt pipeline (T3/T4-lite):
// 256 blocks (1/CU), 8 waves, wave tile 128x32. A panel (32KB) staged once,
// af[8] hoisted; B: 4 buffers (64KB), lookahead-2. Per iter:
//   stage B_{t+2} -> s_waitcnt vmcnt(4) -> s_barrier -> ds_read -> MFMA.
// vmcnt never drains to 0 in the main loop; the drain-at-barrier serializer
// of __syncthreads is eliminated. Buffer t+2 overwrites the buffer last read
// at iter t-2 (two barriers earlier) - race-free. Ticket-fused finalize.
// ---------------------------------------------------------------------------
__global__ __launch_bounds__(512, 2) void gemm_relu_sum_kernel(
    const unsigned char* __restrict__ wsA,
    const unsigned char* __restrict__ wsP,
    float* __restrict__ partials, const float* __restrict__ diagP,
    int* __restrict__ counter, float* __restrict__ out, float invBB) {
  __shared__ __align__(16) unsigned char ldsA[256 * 128];      // 32 KB
  __shared__ __align__(16) unsigned char ldsB[4][128 * 128];   // 4 x 16 KB
  __shared__ float wpart[8];
  __shared__ int lastFlag;
  const int tid = threadIdx.x;
  const int bid = blockIdx.x;
  const int w = tid >> 6, l = tid & 63;
  const int r16 = l & 15, kg = l >> 4;
  const int wrow = w >> 2, wcol = w & 3;   // wave tile 128 rows x 32 cols
  const int rp = bid >> 3;                 // row panel 0..31 (256 rows)
  const int cg = bid & 7;                  // col group 0..7 (XCD-pinned)

  const unsigned char* gA = wsA + (size_t)rp * 256 * D;
  const unsigned char* gB = wsP + (size_t)(cg * 1024) * D;

  // stage one 128x128 fp8 tile (16KB) into lds buffer: 2 insts/thread
#define STAGE_B(buf, tile)                                                     \
  {                                                                            \
    const unsigned char* gBt = gB + (size_t)(tile) * 128 * D;                  \
    char* lB = (char*)ldsB[buf];                                               \
    _Pragma("unroll") for (int it = 0; it < 2; ++it) {                         \
      const int g = it * 512 + tid;                                            \
      const int r = g >> 3, sl = g & 7;                                        \
      const int goff = r * 128 + ((sl ^ (r & 7)) * 16);                        \
      const int lbase = (it * 512 + w * 64) * 16;                              \
      __builtin_amdgcn_global_load_lds(                                        \
          (const __attribute__((address_space(1))) char*)(gBt + goff),         \
          (__attribute__((address_space(3))) char*)(lB + lbase), 16, 0, 0);    \
    }                                                                          \
  }

  // ---- prologue: A panel (4 insts), B0, B1 (2+2) -> outstanding 8
#pragma unroll
  for (int it = 0; it < 4; ++it) {
    const int g = it * 512 + tid;
    const int r = g >> 3, sl = g & 7;
    const int goff = r * 128 + ((sl ^ (r & 7)) * 16);
    const int lbase = (it * 512 + w * 64) * 16;
    __builtin_amdgcn_global_load_lds(
        (const __attribute__((address_space(1))) char*)(gA + goff),
        (__attribute__((address_space(3))) char*)((char*)ldsA + lbase), 16, 0, 0);
  }
  STAGE_B(0, 0)
  STAGE_B(1, 1)

  // A's 4 loads are the oldest: vmcnt(4) completes them (B0,B1 stay in flight)
  asm volatile("s_waitcnt vmcnt(4)" ::: "memory");
  __builtin_amdgcn_s_barrier();

  // ---- hoist A fragments (64 VGPR), reused across all 8 tiles
  i32x8 af[8];
#pragma unroll
  for (int m = 0; m < 8; ++m) {
    const int r = wrow * 128 + m * 16 + r16;
    const unsigned char* base = (const unsigned char*)ldsA + r * 128;
    i32x4 lo = *(const i32x4*)(base + (((2 * kg) ^ (r & 7)) * 16));
    i32x4 hi = *(const i32x4*)(base + (((2 * kg + 1) ^ (r & 7)) * 16));
    af[m] = __builtin_shufflevector(lo, hi, 0, 1, 2, 3, 4, 5, 6, 7);
  }

  float s0 = 0.f, s1 = 0.f, s2 = 0.f, s3 = 0.f;
#pragma unroll
  for (int t = 0; t < 8; ++t) {
    if (t < 6) STAGE_B((t + 2) & 3, t + 2)
    // own B_t loads complete; up to 4 younger (B_{t+1},B_{t+2}) stay in flight
    if (t < 6)      asm volatile("s_waitcnt vmcnt(4)" ::: "memory");
    else if (t == 6) asm volatile("s_waitcnt vmcnt(2)" ::: "memory");
    else             asm volatile("s_waitcnt vmcnt(0)" ::: "memory");
    __builtin_amdgcn_s_barrier();   // all waves' B_t chunks now in LDS

    const unsigned char* lB = (const unsigned char*)ldsB[t & 3];
    i32x8 bfr[2];
#pragma unroll
    for (int n = 0; n < 2; ++n) {
      const int r = wcol * 32 + n * 16 + r16;
      const unsigned char* base = lB + r * 128;
      i32x4 lo = *(const i32x4*)(base + (((2 * kg) ^ (r & 7)) * 16));
      i32x4 hi = *(const i32x4*)(base + (((2 * kg + 1) ^ (r & 7)) * 16));
      bfr[n] = __builtin_shufflevector(lo, hi, 0, 1, 2, 3, 4, 5, 6, 7);
    }

    f32x4 acc[8][2] = {};
    __builtin_amdgcn_s_setprio(1);
#pragma unroll
    for (int m = 0; m < 8; ++m)
#pragma unroll
      for (int n = 0; n < 2; ++n)
        acc[m][n] = __builtin_amdgcn_mfma_scale_f32_16x16x128_f8f6f4(
            af[m], bfr[n], acc[m][n], 0, 0,   // cbsz=fp8, blgp=fp8
            0, 0x7f7f7f7f, 0, 0x7f7f7f7f);    // scales = 1.0
    __builtin_amdgcn_s_setprio(0);

#pragma unroll
    for (int m = 0; m < 8; ++m)
#pragma unroll
      for (int n = 0; n < 2; ++n) {
        s0 += fmaxf(acc[m][n][0], 0.f);
        s1 += fmaxf(acc[m][n][1], 0.f);
        s2 += fmaxf(acc[m][n][2], 0.f);
        s3 += fmaxf(acc[m][n][3], 0.f);
      }
    // no trailing barrier: next iter's stage targets buf (t+3)&3, whose
    // readers (iter t-1) all passed this iter's top barrier already.
  }

  // ---- block partial + ticket-fused finalize
  float s = (s0 + s1) + (s2 + s3);
#pragma unroll
  for (int off = 32; off >= 1; off >>= 1) s += __shfl_xor(s, off);
  if (l == 0) wpart[w] = s;
  __syncthreads();
  if (tid == 0) {
    float b = 0.f;
#pragma unroll
    for (int i = 0; i < 8; ++i) b += wpart[i];
    __hip_atomic_store(&partials[bid], b, __ATOMIC_RELAXED,
                       __HIP_MEMORY_SCOPE_AGENT);
    __threadfence();
    const int ticket = __hip_atomic_fetch_add(counter, 1, __ATOMIC_ACQ_REL,
                                              __HIP_MEMORY_SCOPE_AGENT);
    lastFlag = (ticket == NBLK - 1) ? 1 : 0;
  }
  __syncthreads();

  if (lastFlag) {
    __threadfence();
    float v = diagP[tid];   // 512 diag partials (tid 0..511)
    if (tid < NBLK)
      v += __hip_atomic_load(&partials[tid], __ATOMIC_RELAXED,
                             __HIP_MEMORY_SCOPE_AGENT);
#pragma unroll
    for (int off = 32; off >= 1; off >>= 1) v += __shfl_xor(v, off);
    if (l == 0) wpart[w] = v;
    __syncthreads();
    if (tid == 0) {
      float tot = 0.f;
#pragma unroll
      for (int i = 0; i < 8; ++i) tot += wpart[i];
      out[0] = tot * invBB;
    }
  }
#undef STAGE_B
}

extern "C" void kernel_launch(void* const* d_in, const int* in_sizes, int n_in,
                              void* d_out, int out_size, void* d_ws, size_t ws_size,
                              hipStream_t stream) {
  const float* pos = (const float*)d_in[0];  // hid_positive
  const float* anc = (const float*)d_in[1];  // hid_anchor
  const int B = in_sizes[0] / D;             // 8192

  char* ws = (char*)d_ws;
  unsigned char* wsA = (unsigned char*)ws;                      // B*D fp8 (1MB)
  unsigned char* wsP = (unsigned char*)(ws + (size_t)B * D);    // B*D fp8 (1MB)
  float* partials = (float*)(ws + (size_t)2 * B * D);           // 256 f32
  float* diagP = partials + NBLK;                               // 512 f32
  int* counter = (int*)(diagP + 512);

  const int nDiag = B / 16;                  // 512
  const float invBB = 1.0f / ((float)B * (float)B);

  normalize_diag_kernel<<<nDiag, 256, 0, stream>>>(anc, pos, wsA, wsP, diagP,
                                                   counter);
  gemm_relu_sum_kernel<<<NBLK, 512, 0, stream>>>(wsA, wsP, partials, diagP,
                                                 counter, (float*)d_out, invBB);
}